// Round 8
// baseline (1877.654 us; speedup 1.0000x reference)
//
#include <hip/hip_runtime.h>
#include <hip/hip_bf16.h>
#include <string.h>

typedef __bf16 bf16;
typedef __bf16 bf16x8 __attribute__((ext_vector_type(8)));
typedef __bf16 bf16x4 __attribute__((ext_vector_type(4)));
typedef __bf16 bf16x2 __attribute__((ext_vector_type(2)));
typedef float f32x4 __attribute__((ext_vector_type(4)));
typedef float f32x2 __attribute__((ext_vector_type(2)));
typedef unsigned long long ull;

// ---------------------------------------------------------------------------
// Weight conversion fp32 -> bf16, and combined bias bih+bhh
// ---------------------------------------------------------------------------
__global__ void convert_w(const float* __restrict__ Wih, const float* __restrict__ Whh,
                          const float* __restrict__ decW, const float* __restrict__ bih,
                          const float* __restrict__ bhh,
                          bf16* __restrict__ WihB, bf16* __restrict__ WhhB,
                          bf16* __restrict__ decWB, float* __restrict__ bias) {
    int idx = blockIdx.x * 256 + threadIdx.x;
    const int NW = 2 * 2048 * 512;           // 2097152 (both layers)
    if (idx < NW) {
        WihB[idx] = (bf16)Wih[idx];
    } else if (idx < 2 * NW) {
        WhhB[idx - NW] = (bf16)Whh[idx - NW];
    } else if (idx < 2 * NW + 512 * 512) {
        decWB[idx - 2 * NW] = (bf16)decW[idx - 2 * NW];
    } else if (idx < 2 * NW + 512 * 512 + 4096) {
        int j = idx - (2 * NW + 512 * 512);
        bias[j] = bih[j] + bhh[j];
    }
}

// ---------------------------------------------------------------------------
// inp[b,t,h] = emb[trg[b,t], h] + y[b]*yW[h] + yb[h]   (bf16 out)
// ---------------------------------------------------------------------------
__global__ void prep_inp(const int* __restrict__ x, const float* __restrict__ y,
                         const float* __restrict__ emb, const float* __restrict__ yW,
                         const float* __restrict__ yb, bf16* __restrict__ inp) {
    int idx = blockIdx.x * 256 + threadIdx.x;   // total 65536*64
    int bt = idx >> 6;
    int h0 = (idx & 63) * 8;
    int b = bt >> 7, t = bt & 127;
    int trg = (t == 0) ? 512 : x[b * 128 + t - 1];
    float yv = y[b];
    const float* e = emb + (size_t)trg * 512 + h0;
    bf16x8 v;
    #pragma unroll
    for (int i = 0; i < 8; ++i) v[i] = (bf16)(e[i] + yv * yW[h0 + i] + yb[h0 + i]);
    *(bf16x8*)&inp[(size_t)bt * 512 + h0] = v;
}

// ---------------------------------------------------------------------------
// C[M,N] = A[M,512] * W[N,512]^T + bias[N]   (proven 128x128 MFMA tile)
// ---------------------------------------------------------------------------
template <bool OUT_BF16>
__global__ __launch_bounds__(256) void gemm_bt(const bf16* __restrict__ A,
                                               const bf16* __restrict__ W,
                                               const float* __restrict__ bias,
                                               void* __restrict__ Cout, int M, int N) {
    constexpr int K = 512;
    __shared__ bf16 As[128][40];
    __shared__ bf16 Ws[128][40];
    int bid = blockIdx.x;
    int nTiles = N / 128;
    int m0 = (bid / nTiles) * 128;
    int n0 = (bid % nTiles) * 128;
    int tid = threadIdx.x;
    int wave = tid >> 6, lane = tid & 63;
    int quad = lane >> 4, l16 = lane & 15;
    int wm = (wave & 1) * 64, wn = (wave >> 1) * 64;
    f32x4 acc[4][4] = {};

    for (int k0 = 0; k0 < K; k0 += 32) {
        __syncthreads();
        #pragma unroll
        for (int r = 0; r < 2; ++r) {
            int c = tid + 256 * r;
            int row = c >> 2, col = (c & 3) * 8;
            *(bf16x8*)&As[row][col] = *(const bf16x8*)&A[(size_t)(m0 + row) * K + k0 + col];
            *(bf16x8*)&Ws[row][col] = *(const bf16x8*)&W[(size_t)(n0 + row) * K + k0 + col];
        }
        __syncthreads();
        bf16x8 af[4], bfr[4];
        #pragma unroll
        for (int i = 0; i < 4; ++i) af[i] = *(const bf16x8*)&As[wm + i * 16 + l16][quad * 8];
        #pragma unroll
        for (int i = 0; i < 4; ++i) bfr[i] = *(const bf16x8*)&Ws[wn + i * 16 + l16][quad * 8];
        #pragma unroll
        for (int mt = 0; mt < 4; ++mt)
            #pragma unroll
            for (int nt = 0; nt < 4; ++nt)
                acc[mt][nt] = __builtin_amdgcn_mfma_f32_16x16x32_bf16(af[mt], bfr[nt], acc[mt][nt], 0, 0, 0);
    }

    #pragma unroll
    for (int mt = 0; mt < 4; ++mt)
        #pragma unroll
        for (int nt = 0; nt < 4; ++nt) {
            int row = m0 + wm + mt * 16 + quad * 4;
            int col = n0 + wn + nt * 16 + l16;
            float bv = bias[col];
            #pragma unroll
            for (int i = 0; i < 4; ++i) {
                float v = acc[mt][nt][i] + bv;
                if (OUT_BF16) ((bf16*)Cout)[(size_t)(row + i) * N + col] = (bf16)v;
                else          ((float*)Cout)[(size_t)(row + i) * N + col] = v;
            }
        }
}

// ---------------------------------------------------------------------------
// Persistent LSTM scan, fence-free producer/consumer. Round-8 structure:
// r6 anchor (grid 256 = 32 groups x 8 q-blocks, 16 rows x 64 cols, 538us)
// with the per-step critical path trimmed:
//  * per-WAVE poll: lane l loads flag cnt[l] (64 flags/group = 8 blocks x
//    8 waves), __all(v>=tgt). No tid0 poll, no wake syncthreads.
//  * per-WAVE flags: each wave drains its own h stores (vmcnt(0)), lane0
//    stores cnt[q*8+w]=t+2. No drain barrier, no tid0 serialization.
//  * own-slice shortcut: epilogue writes h into Hs directly; loaders skip
//    own-q columns (no MALL round trip for the block's own 64 cols).
// Barriers/step: 2 (Hs-ready, gs-ready) - was 4.
// Safety: (a) wave X's afr reads at t precede its gs write / barrier-2 /
// flag(t+2); peer waves only overwrite Hs/gs for t+1 after their poll sees
// ALL flags >= t+2 -> poll is the cross-step fence. (b) LDS visibility of
// epilogue's own-slice Hs writes is ordered by the writer's barrier-1
// arrival at t+1 (syncthreads flushes lgkm). (c) ping-pong h buffers
// tolerate the 1-step skew exactly as the proven anchors.
// ---------------------------------------------------------------------------
#define HS_STRIDE 520

__global__ __launch_bounds__(512, 2) void lstm_scan(const bf16* __restrict__ xg,
                                                    const bf16* __restrict__ Wh,
                                                    bf16* __restrict__ hA,
                                                    bf16* __restrict__ hB,
                                                    bf16* __restrict__ h_all,
                                                    unsigned* __restrict__ barcnt) {
    constexpr int T = 128;
    __shared__ bf16 Hs[16][HS_STRIDE];
    __shared__ float gs[8][16][36];    // stride 36: 8B-aligned rows, bank rot
    int tid = threadIdx.x;
    int bt = blockIdx.x >> 3;          // batch tile 0..31 (16 rows)
    int q  = blockIdx.x & 7;           // hh tile (64 cols) 0..7
    int b0 = bt * 16;
    int n0 = q * 64;
    int w = tid >> 6, lane = tid & 63;
    int quad = lane >> 4, l16 = lane & 15;
    int g = w >> 1, s = w & 1;         // gate, 32-col half
    unsigned* cnt = barcnt + bt * 64;  // 64 wave-flags per group (256B line)

    // Whh slice -> registers (once): rows g*512 + n0 + 32s .. +31
    bf16x8 wreg[2][16];
    const bf16* wbase = Wh + ((size_t)g * 512 + n0 + 32 * s) * 512;
    #pragma unroll
    for (int nt = 0; nt < 2; ++nt)
        #pragma unroll
        for (int kc = 0; kc < 16; ++kc)
            wreg[nt][kc] = *(const bf16x8*)&wbase[(size_t)(nt * 16 + l16) * 512 + kc * 32 + quad * 8];

    // epilogue mapping: 512 threads <-> 16 batch x 64 cols, 2 cols each
    int m = tid >> 5;                  // 0..15
    int nl0 = (tid & 31) * 2;          // 0..62
    int b = b0 + m;
    int half = nl0 >> 5;               // which 32-col half
    int nn = nl0 & 31;                 // col within half
    float cc[2] = {0.f, 0.f};

    // init: zero own hA slice (global, peers read at t=0), zero Hs (own
    // slice feeds own t=0 MFMA), drain, block barrier, per-wave flag=1
    __hip_atomic_store((unsigned*)&hA[(size_t)b * 512 + n0 + nl0], 0u,
                       __ATOMIC_RELAXED, __HIP_MEMORY_SCOPE_AGENT);
    #pragma unroll
    for (int i = 0; i < 4; ++i) {
        int idx = i * 512 + tid;
        *(ull*)&Hs[idx >> 7][(idx & 127) * 4] = 0ull;
    }
    asm volatile("s_waitcnt vmcnt(0)" ::: "memory");
    __syncthreads();
    if (lane == 0) __hip_atomic_store(cnt + q * 8 + w, 1u,
                                      __ATOMIC_RELAXED, __HIP_MEMORY_SCOPE_AGENT);

    const bf16* hp = hA;
    bf16* hn = hB;

    for (int t = 0; t < T; ++t) {
        // prefetch this step's xg into registers (overlaps the poll)
        size_t xrow = ((size_t)b * T + t) * 2048 + n0 + nl0;
        bf16x2 xv[4];
        #pragma unroll
        for (int gg = 0; gg < 4; ++gg) xv[gg] = *(const bf16x2*)&xg[xrow + (size_t)gg * 512];

        // per-wave poll: all 64 wave-flags of the group >= t+1
        {
            unsigned tgt = (unsigned)(t + 1);
            for (;;) {
                unsigned v = __hip_atomic_load(cnt + lane, __ATOMIC_RELAXED,
                                               __HIP_MEMORY_SCOPE_AGENT);
                if (__all(v >= tgt)) break;
                __builtin_amdgcn_s_sleep(1);
            }
        }

        // coherent read h_prev (skip own 64-col slice: epilogue keeps it in Hs)
        #pragma unroll
        for (int i = 0; i < 4; ++i) {
            int idx = i * 512 + tid;           // 2048 b64 chunks
            int row = idx >> 7, colb = idx & 127;
            if ((colb >> 4) != q) {
                ull v = __hip_atomic_load((const ull*)&hp[(size_t)(b0 + row) * 512 + colb * 4],
                                          __ATOMIC_RELAXED, __HIP_MEMORY_SCOPE_AGENT);
                *(ull*)&Hs[row][colb * 4] = v;
            }
        }
        __syncthreads();                       // barrier 1: Hs ready

        // MFMA over K=512: out 16 batch x 32 cols per wave
        f32x4 acc0 = {}, acc1 = {};
        #pragma unroll
        for (int kc = 0; kc < 16; ++kc) {
            bf16x8 af0 = *(const bf16x8*)&Hs[l16][kc * 32 + quad * 8];
            acc0 = __builtin_amdgcn_mfma_f32_16x16x32_bf16(af0, wreg[0][kc], acc0, 0, 0, 0);
            acc1 = __builtin_amdgcn_mfma_f32_16x16x32_bf16(af0, wreg[1][kc], acc1, 0, 0, 0);
        }
        #pragma unroll
        for (int i = 0; i < 4; ++i) {
            gs[w][quad * 4 + i][s * 0 + 0 * 16 + l16] = acc0[i];   // cols 32s+0..15
            gs[w][quad * 4 + i][1 * 16 + l16] = acc1[i];           // cols 32s+16..31
        }
        __syncthreads();                       // barrier 2: gs ready

        // gates + state update (c register-resident); vectorized gs reads
        f32x2 g0 = *(const f32x2*)&gs[0 * 2 + half][m][nn];
        f32x2 g1 = *(const f32x2*)&gs[1 * 2 + half][m][nn];
        f32x2 g2 = *(const f32x2*)&gs[2 * 2 + half][m][nn];
        f32x2 g3 = *(const f32x2*)&gs[3 * 2 + half][m][nn];
        bf16x2 hv;
        #pragma unroll
        for (int ii = 0; ii < 2; ++ii) {
            float gi = g0[ii] + (float)xv[0][ii];
            float gf = g1[ii] + (float)xv[1][ii];
            float gg = g2[ii] + (float)xv[2][ii];
            float go = g3[ii] + (float)xv[3][ii];
            float iv = 1.f / (1.f + __expf(-gi));
            float fv = 1.f / (1.f + __expf(-gf));
            float gv = 1.f - 2.f / (1.f + __expf(2.f * gg));    // tanh
            float ov = 1.f / (1.f + __expf(-go));
            float cn = fv * cc[ii] + iv * gv;
            float th = 1.f - 2.f / (1.f + __expf(2.f * cn));    // tanh
            cc[ii] = cn;
            hv[ii] = (bf16)(ov * th);
        }
        // own-slice into LDS (consumed by own block next step)
        *(bf16x2*)&Hs[m][n0 + nl0] = hv;
        // peer-visible store + per-wave drain + per-wave flag
        unsigned hbits;
        memcpy(&hbits, &hv, 4);
        __hip_atomic_store((unsigned*)&hn[(size_t)b * 512 + n0 + nl0], hbits,
                           __ATOMIC_RELAXED, __HIP_MEMORY_SCOPE_AGENT);
        asm volatile("s_waitcnt vmcnt(0)" ::: "memory");
        if (lane == 0) __hip_atomic_store(cnt + q * 8 + w, (unsigned)(t + 2),
                                          __ATOMIC_RELAXED, __HIP_MEMORY_SCOPE_AGENT);
        // HBM copy for next dispatch: off the drain path
        *(bf16x2*)&h_all[((size_t)b * T + t) * 512 + n0 + nl0] = hv;

        const bf16* tmp = hp; hp = hn; hn = (bf16*)tmp;
    }
}

// ---------------------------------------------------------------------------
extern "C" void kernel_launch(void* const* d_in, const int* in_sizes, int n_in,
                              void* d_out, int out_size, void* d_ws, size_t ws_size,
                              hipStream_t stream) {
    const int*   x    = (const int*)d_in[0];
    const float* y    = (const float*)d_in[1];
    const float* emb  = (const float*)d_in[2];
    const float* yW   = (const float*)d_in[3];
    const float* yb   = (const float*)d_in[4];
    const float* Wih  = (const float*)d_in[5];
    const float* Whh  = (const float*)d_in[6];
    const float* bih  = (const float*)d_in[7];
    const float* bhh  = (const float*)d_in[8];
    const float* decW = (const float*)d_in[9];
    const float* decb = (const float*)d_in[10];
    float* out = (float*)d_out;

    char* ws = (char*)d_ws;
    size_t off = 0;
    auto alloc = [&](size_t bytes) {
        char* p = ws + off;
        off += (bytes + 255) & ~(size_t)255;
        return p;
    };
    bf16*  inp   = (bf16*)alloc(65536ull * 512 * 2);    //  64 MB
    bf16*  xg    = (bf16*)alloc(65536ull * 2048 * 2);   // 256 MB
    bf16*  WihB  = (bf16*)alloc(2097152ull * 2);
    bf16*  WhhB  = (bf16*)alloc(2097152ull * 2);
    bf16*  decWB = (bf16*)alloc(262144ull * 2);
    float* bias  = (float*)alloc(4096ull * 4);
    bf16*  hA    = (bf16*)alloc(512ull * 512 * 2);
    bf16*  hB    = (bf16*)alloc(512ull * 512 * 2);
    unsigned* cnt = (unsigned*)alloc(2 * 32 * 64 * 4);  // 2 layers x 32 groups x 64 wave-flags

    hipMemsetAsync(cnt, 0, 2 * 32 * 64 * 4, stream);
    convert_w<<<17424, 256, 0, stream>>>(Wih, Whh, decW, bih, bhh, WihB, WhhB, decWB, bias);
    prep_inp<<<16384, 256, 0, stream>>>(x, y, emb, yW, yb, inp);

    const size_t LSTRIDE = 2048ull * 512;   // per-layer weight elements
    for (int l = 0; l < 2; ++l) {
        gemm_bt<true><<<512 * 16, 256, 0, stream>>>(inp, WihB + (size_t)l * LSTRIDE,
                                                    bias + l * 2048, xg, 65536, 2048);
        lstm_scan<<<256, 512, 0, stream>>>(xg, WhhB + (size_t)l * LSTRIDE,
                                           hA, hB, inp, cnt + (size_t)l * 32 * 64);
    }
    gemm_bt<false><<<512 * 4, 256, 0, stream>>>(inp, decWB, decb, out, 65536, 512);
}

// Round 9
// 1718.432 us; speedup vs baseline: 1.0927x; 1.0927x over previous
//
#include <hip/hip_runtime.h>
#include <hip/hip_bf16.h>
#include <string.h>

typedef __bf16 bf16;
typedef __bf16 bf16x8 __attribute__((ext_vector_type(8)));
typedef __bf16 bf16x4 __attribute__((ext_vector_type(4)));
typedef __bf16 bf16x2 __attribute__((ext_vector_type(2)));
typedef float f32x4 __attribute__((ext_vector_type(4)));
typedef float f32x2 __attribute__((ext_vector_type(2)));
typedef unsigned long long ull;

// ---------------------------------------------------------------------------
// Weight conversion fp32 -> bf16, and combined bias bih+bhh
// ---------------------------------------------------------------------------
__global__ void convert_w(const float* __restrict__ Wih, const float* __restrict__ Whh,
                          const float* __restrict__ decW, const float* __restrict__ bih,
                          const float* __restrict__ bhh,
                          bf16* __restrict__ WihB, bf16* __restrict__ WhhB,
                          bf16* __restrict__ decWB, float* __restrict__ bias) {
    int idx = blockIdx.x * 256 + threadIdx.x;
    const int NW = 2 * 2048 * 512;           // 2097152 (both layers)
    if (idx < NW) {
        WihB[idx] = (bf16)Wih[idx];
    } else if (idx < 2 * NW) {
        WhhB[idx - NW] = (bf16)Whh[idx - NW];
    } else if (idx < 2 * NW + 512 * 512) {
        decWB[idx - 2 * NW] = (bf16)decW[idx - 2 * NW];
    } else if (idx < 2 * NW + 512 * 512 + 4096) {
        int j = idx - (2 * NW + 512 * 512);
        bias[j] = bih[j] + bhh[j];
    }
}

// ---------------------------------------------------------------------------
// inp[b,t,h] = emb[trg[b,t], h] + y[b]*yW[h] + yb[h]   (bf16 out)
// ---------------------------------------------------------------------------
__global__ void prep_inp(const int* __restrict__ x, const float* __restrict__ y,
                         const float* __restrict__ emb, const float* __restrict__ yW,
                         const float* __restrict__ yb, bf16* __restrict__ inp) {
    int idx = blockIdx.x * 256 + threadIdx.x;   // total 65536*64
    int bt = idx >> 6;
    int h0 = (idx & 63) * 8;
    int b = bt >> 7, t = bt & 127;
    int trg = (t == 0) ? 512 : x[b * 128 + t - 1];
    float yv = y[b];
    const float* e = emb + (size_t)trg * 512 + h0;
    bf16x8 v;
    #pragma unroll
    for (int i = 0; i < 8; ++i) v[i] = (bf16)(e[i] + yv * yW[h0 + i] + yb[h0 + i]);
    *(bf16x8*)&inp[(size_t)bt * 512 + h0] = v;
}

// ---------------------------------------------------------------------------
// C[M,N] = A[M,512] * W[N,512]^T + bias[N]   (proven 128x128 MFMA tile)
// ---------------------------------------------------------------------------
template <bool OUT_BF16>
__global__ __launch_bounds__(256) void gemm_bt(const bf16* __restrict__ A,
                                               const bf16* __restrict__ W,
                                               const float* __restrict__ bias,
                                               void* __restrict__ Cout, int M, int N) {
    constexpr int K = 512;
    __shared__ bf16 As[128][40];
    __shared__ bf16 Ws[128][40];
    int bid = blockIdx.x;
    int nTiles = N / 128;
    int m0 = (bid / nTiles) * 128;
    int n0 = (bid % nTiles) * 128;
    int tid = threadIdx.x;
    int wave = tid >> 6, lane = tid & 63;
    int quad = lane >> 4, l16 = lane & 15;
    int wm = (wave & 1) * 64, wn = (wave >> 1) * 64;
    f32x4 acc[4][4] = {};

    for (int k0 = 0; k0 < K; k0 += 32) {
        __syncthreads();
        #pragma unroll
        for (int r = 0; r < 2; ++r) {
            int c = tid + 256 * r;
            int row = c >> 2, col = (c & 3) * 8;
            *(bf16x8*)&As[row][col] = *(const bf16x8*)&A[(size_t)(m0 + row) * K + k0 + col];
            *(bf16x8*)&Ws[row][col] = *(const bf16x8*)&W[(size_t)(n0 + row) * K + k0 + col];
        }
        __syncthreads();
        bf16x8 af[4], bfr[4];
        #pragma unroll
        for (int i = 0; i < 4; ++i) af[i] = *(const bf16x8*)&As[wm + i * 16 + l16][quad * 8];
        #pragma unroll
        for (int i = 0; i < 4; ++i) bfr[i] = *(const bf16x8*)&Ws[wn + i * 16 + l16][quad * 8];
        #pragma unroll
        for (int mt = 0; mt < 4; ++mt)
            #pragma unroll
            for (int nt = 0; nt < 4; ++nt)
                acc[mt][nt] = __builtin_amdgcn_mfma_f32_16x16x32_bf16(af[mt], bfr[nt], acc[mt][nt], 0, 0, 0);
    }

    #pragma unroll
    for (int mt = 0; mt < 4; ++mt)
        #pragma unroll
        for (int nt = 0; nt < 4; ++nt) {
            int row = m0 + wm + mt * 16 + quad * 4;
            int col = n0 + wn + nt * 16 + l16;
            float bv = bias[col];
            #pragma unroll
            for (int i = 0; i < 4; ++i) {
                float v = acc[mt][nt][i] + bv;
                if (OUT_BF16) ((bf16*)Cout)[(size_t)(row + i) * N + col] = (bf16)v;
                else          ((float*)Cout)[(size_t)(row + i) * N + col] = v;
            }
        }
}

// ---------------------------------------------------------------------------
// Persistent LSTM scan, fence-free producer/consumer. Round-9 structure:
// r6 anchor (grid 256 = 32 groups x 8 q-blocks, 16 rows x 64 cols, 538us)
// plus the two changes r8 validated, minus the one it disproved:
//  * per-WAVE flags (64/group): each wave drains its own h stores
//    (vmcnt(0)), lane0 stores cnt[q*8+w]=t+2 -> no drain barrier, no tid0
//    serialization.  [kept]
//  * own-slice shortcut: epilogue writes h into Hs directly; loaders skip
//    own-q columns (FETCH -6%, r8-verified).  [kept]
//  * poll: WAVE 0 ONLY (lane l loads cnt[l], __all) + wake syncthreads.
//    r8's all-wave poll multiplied flag traffic 8x and regressed; this
//    restores r6's one-poller-per-block footprint.  [reverted]
// Barriers/step: 3 (wake, Hs-ready, gs-ready).
// Safety: poll-as-cross-step-fence (a wave passes poll for t+1 only after
// ALL 64 waves of the group set flag t+2, i.e. everyone finished step t and
// drained stores); LDS visibility of own-slice Hs writes and loader writes
// is ordered by the wake/Hs barriers; ping-pong h buffers tolerate the
// 1-step skew exactly as the proven anchors.
// ---------------------------------------------------------------------------
#define HS_STRIDE 520

__global__ __launch_bounds__(512, 2) void lstm_scan(const bf16* __restrict__ xg,
                                                    const bf16* __restrict__ Wh,
                                                    bf16* __restrict__ hA,
                                                    bf16* __restrict__ hB,
                                                    bf16* __restrict__ h_all,
                                                    unsigned* __restrict__ barcnt) {
    constexpr int T = 128;
    __shared__ bf16 Hs[16][HS_STRIDE];
    __shared__ float gs[8][16][36];    // stride 36: 8B-aligned rows, bank rot
    int tid = threadIdx.x;
    int bt = blockIdx.x >> 3;          // batch tile 0..31 (16 rows)
    int q  = blockIdx.x & 7;           // hh tile (64 cols) 0..7
    int b0 = bt * 16;
    int n0 = q * 64;
    int w = tid >> 6, lane = tid & 63;
    int quad = lane >> 4, l16 = lane & 15;
    int g = w >> 1, s = w & 1;         // gate, 32-col half
    unsigned* cnt = barcnt + bt * 64;  // 64 wave-flags per group (256B line)

    // Whh slice -> registers (once): rows g*512 + n0 + 32s .. +31
    bf16x8 wreg[2][16];
    const bf16* wbase = Wh + ((size_t)g * 512 + n0 + 32 * s) * 512;
    #pragma unroll
    for (int nt = 0; nt < 2; ++nt)
        #pragma unroll
        for (int kc = 0; kc < 16; ++kc)
            wreg[nt][kc] = *(const bf16x8*)&wbase[(size_t)(nt * 16 + l16) * 512 + kc * 32 + quad * 8];

    // epilogue mapping: 512 threads <-> 16 batch x 64 cols, 2 cols each
    int m = tid >> 5;                  // 0..15
    int nl0 = (tid & 31) * 2;          // 0..62
    int b = b0 + m;
    int half = nl0 >> 5;               // which 32-col half
    int nn = nl0 & 31;                 // col within half
    float cc[2] = {0.f, 0.f};

    // init: zero own hA slice (global, peers read at t=0), zero Hs (own
    // slice feeds own t=0 MFMA), drain, block barrier, per-wave flag=1
    __hip_atomic_store((unsigned*)&hA[(size_t)b * 512 + n0 + nl0], 0u,
                       __ATOMIC_RELAXED, __HIP_MEMORY_SCOPE_AGENT);
    #pragma unroll
    for (int i = 0; i < 4; ++i) {
        int idx = i * 512 + tid;
        *(ull*)&Hs[idx >> 7][(idx & 127) * 4] = 0ull;
    }
    asm volatile("s_waitcnt vmcnt(0)" ::: "memory");
    __syncthreads();
    if (lane == 0) __hip_atomic_store(cnt + q * 8 + w, 1u,
                                      __ATOMIC_RELAXED, __HIP_MEMORY_SCOPE_AGENT);

    const bf16* hp = hA;
    bf16* hn = hB;

    for (int t = 0; t < T; ++t) {
        // prefetch this step's xg into registers (overlaps the poll)
        size_t xrow = ((size_t)b * T + t) * 2048 + n0 + nl0;
        bf16x2 xv[4];
        #pragma unroll
        for (int gg = 0; gg < 4; ++gg) xv[gg] = *(const bf16x2*)&xg[xrow + (size_t)gg * 512];

        // poll: wave 0 only (lane l <-> flag l), then wake the block
        if (w == 0) {
            unsigned tgt = (unsigned)(t + 1);
            for (;;) {
                unsigned v = __hip_atomic_load(cnt + lane, __ATOMIC_RELAXED,
                                               __HIP_MEMORY_SCOPE_AGENT);
                if (__all(v >= tgt)) break;
                __builtin_amdgcn_s_sleep(1);
            }
        }
        __syncthreads();                       // wake

        // coherent read h_prev (skip own 64-col slice: epilogue keeps it in Hs)
        #pragma unroll
        for (int i = 0; i < 4; ++i) {
            int idx = i * 512 + tid;           // 2048 b64 chunks
            int row = idx >> 7, colb = idx & 127;
            if ((colb >> 4) != q) {
                ull v = __hip_atomic_load((const ull*)&hp[(size_t)(b0 + row) * 512 + colb * 4],
                                          __ATOMIC_RELAXED, __HIP_MEMORY_SCOPE_AGENT);
                *(ull*)&Hs[row][colb * 4] = v;
            }
        }
        __syncthreads();                       // Hs ready

        // MFMA over K=512: out 16 batch x 32 cols per wave
        f32x4 acc0 = {}, acc1 = {};
        #pragma unroll
        for (int kc = 0; kc < 16; ++kc) {
            bf16x8 af0 = *(const bf16x8*)&Hs[l16][kc * 32 + quad * 8];
            acc0 = __builtin_amdgcn_mfma_f32_16x16x32_bf16(af0, wreg[0][kc], acc0, 0, 0, 0);
            acc1 = __builtin_amdgcn_mfma_f32_16x16x32_bf16(af0, wreg[1][kc], acc1, 0, 0, 0);
        }
        #pragma unroll
        for (int i = 0; i < 4; ++i) {
            gs[w][quad * 4 + i][l16] = acc0[i];          // cols 32s + 0..15
            gs[w][quad * 4 + i][16 + l16] = acc1[i];     // cols 32s + 16..31
        }
        __syncthreads();                       // gs ready

        // gates + state update (c register-resident); vectorized gs reads
        f32x2 g0 = *(const f32x2*)&gs[0 * 2 + half][m][nn];
        f32x2 g1 = *(const f32x2*)&gs[1 * 2 + half][m][nn];
        f32x2 g2 = *(const f32x2*)&gs[2 * 2 + half][m][nn];
        f32x2 g3 = *(const f32x2*)&gs[3 * 2 + half][m][nn];
        bf16x2 hv;
        #pragma unroll
        for (int ii = 0; ii < 2; ++ii) {
            float gi = g0[ii] + (float)xv[0][ii];
            float gf = g1[ii] + (float)xv[1][ii];
            float gg = g2[ii] + (float)xv[2][ii];
            float go = g3[ii] + (float)xv[3][ii];
            float iv = 1.f / (1.f + __expf(-gi));
            float fv = 1.f / (1.f + __expf(-gf));
            float gv = 1.f - 2.f / (1.f + __expf(2.f * gg));    // tanh
            float ov = 1.f / (1.f + __expf(-go));
            float cn = fv * cc[ii] + iv * gv;
            float th = 1.f - 2.f / (1.f + __expf(2.f * cn));    // tanh
            cc[ii] = cn;
            hv[ii] = (bf16)(ov * th);
        }
        // own-slice into LDS (consumed by own block next step)
        *(bf16x2*)&Hs[m][n0 + nl0] = hv;
        // peer-visible store + per-wave drain + per-wave flag
        unsigned hbits;
        memcpy(&hbits, &hv, 4);
        __hip_atomic_store((unsigned*)&hn[(size_t)b * 512 + n0 + nl0], hbits,
                           __ATOMIC_RELAXED, __HIP_MEMORY_SCOPE_AGENT);
        asm volatile("s_waitcnt vmcnt(0)" ::: "memory");
        if (lane == 0) __hip_atomic_store(cnt + q * 8 + w, (unsigned)(t + 2),
                                          __ATOMIC_RELAXED, __HIP_MEMORY_SCOPE_AGENT);
        // HBM copy for next dispatch: off the drain path
        *(bf16x2*)&h_all[((size_t)b * T + t) * 512 + n0 + nl0] = hv;

        const bf16* tmp = hp; hp = hn; hn = (bf16*)tmp;
    }
}

// ---------------------------------------------------------------------------
extern "C" void kernel_launch(void* const* d_in, const int* in_sizes, int n_in,
                              void* d_out, int out_size, void* d_ws, size_t ws_size,
                              hipStream_t stream) {
    const int*   x    = (const int*)d_in[0];
    const float* y    = (const float*)d_in[1];
    const float* emb  = (const float*)d_in[2];
    const float* yW   = (const float*)d_in[3];
    const float* yb   = (const float*)d_in[4];
    const float* Wih  = (const float*)d_in[5];
    const float* Whh  = (const float*)d_in[6];
    const float* bih  = (const float*)d_in[7];
    const float* bhh  = (const float*)d_in[8];
    const float* decW = (const float*)d_in[9];
    const float* decb = (const float*)d_in[10];
    float* out = (float*)d_out;

    char* ws = (char*)d_ws;
    size_t off = 0;
    auto alloc = [&](size_t bytes) {
        char* p = ws + off;
        off += (bytes + 255) & ~(size_t)255;
        return p;
    };
    bf16*  inp   = (bf16*)alloc(65536ull * 512 * 2);    //  64 MB
    bf16*  xg    = (bf16*)alloc(65536ull * 2048 * 2);   // 256 MB
    bf16*  WihB  = (bf16*)alloc(2097152ull * 2);
    bf16*  WhhB  = (bf16*)alloc(2097152ull * 2);
    bf16*  decWB = (bf16*)alloc(262144ull * 2);
    float* bias  = (float*)alloc(4096ull * 4);
    bf16*  hA    = (bf16*)alloc(512ull * 512 * 2);
    bf16*  hB    = (bf16*)alloc(512ull * 512 * 2);
    unsigned* cnt = (unsigned*)alloc(2 * 32 * 64 * 4);  // 2 layers x 32 groups x 64 wave-flags

    hipMemsetAsync(cnt, 0, 2 * 32 * 64 * 4, stream);
    convert_w<<<17424, 256, 0, stream>>>(Wih, Whh, decW, bih, bhh, WihB, WhhB, decWB, bias);
    prep_inp<<<16384, 256, 0, stream>>>(x, y, emb, yW, yb, inp);

    const size_t LSTRIDE = 2048ull * 512;   // per-layer weight elements
    for (int l = 0; l < 2; ++l) {
        gemm_bt<true><<<512 * 16, 256, 0, stream>>>(inp, WihB + (size_t)l * LSTRIDE,
                                                    bias + l * 2048, xg, 65536, 2048);
        lstm_scan<<<256, 512, 0, stream>>>(xg, WhhB + (size_t)l * LSTRIDE,
                                           hA, hB, inp, cnt + (size_t)l * 32 * 64);
    }
    gemm_bt<false><<<512 * 4, 256, 0, stream>>>(inp, decWB, decb, out, 65536, 512);
}